// Round 8
// baseline (377.985 us; speedup 1.0000x reference)
//
#include <hip/hip_runtime.h>
#include <math.h>

// Problem constants (B=8192 rows, D=256 features)
#define NB 8192
#define ND 256

using bf16x8 = __attribute__((ext_vector_type(8))) short;  // 8 bf16 in 4 VGPRs
using f32x4  = __attribute__((ext_vector_type(4))) float;  // MFMA C/D frag

#define POS2 0.99998000f   // (1 - 1e-5)^2, pos_mask_ threshold in d2 space
#define F_INF  __int_as_float(0x7f800000)
#define F_NINF __int_as_float(0xff800000)

__device__ __forceinline__ unsigned short f2bf(float x) {  // RNE fp32->bf16
    unsigned u = __float_as_uint(x);
    return (unsigned short)((u + 0x7fffu + ((u >> 16) & 1u)) >> 16);
}
__device__ __forceinline__ float bf2f(unsigned short b) {
    return __uint_as_float(((unsigned)b) << 16);
}

// fnb2 layout: fragment-major. For 16-row block R (0..511) and kb (K=32
// chunk, 0..7), a contiguous 1 KB unit holds the 64 lanes' 16-B fragments:
//   unit index = R*8 + kb   (8 units per row-block — NOT 16; round-7 bug)
//   unit base  = (R*8 + kb) * 512 ushorts
//   lane (q=lane>>4, c16=lane&15) owns ushorts [lane*8, lane*8+8)
//     = row (R*16+c16), k [kb*32+q*8, +8).
// Total: 512 * 8 * 512 ushorts = NB*ND exactly (4 MB).
// Every MFMA A/B fragment load becomes global_load_dwordx4 at
// uniform_base + lane*16 — perfectly coalesced, no LDS needed.

// ------------------------------------------- normalize (+ init folded in)
__global__ void normalize_kernel(const float* __restrict__ feats,
                                 unsigned short* __restrict__ fnb2,
                                 float* __restrict__ sq,
                                 float* minpos_d2, float* maxneg_d2,
                                 float* negsum, float* possum, float* poscnt,
                                 float* out) {
    int row = blockIdx.x * 4 + (threadIdx.x >> 6);
    int lane = threadIdx.x & 63;
    float4 v = ((const float4*)(feats + (size_t)row * ND))[lane];
    float s = v.x*v.x + v.y*v.y + v.z*v.z + v.w*v.w;
    #pragma unroll
    for (int off = 32; off > 0; off >>= 1) s += __shfl_xor(s, off, 64);
    float inv = 1.0f / (sqrtf(s) + 1e-12f);
    ushort4 w;
    w.x = f2bf(v.x * inv); w.y = f2bf(v.y * inv);
    w.z = f2bf(v.z * inv); w.w = f2bf(v.w * inv);
    // lane holds k = lane*4 .. lane*4+3 -> kb = lane>>3, q = (lane&7)>>1,
    // j = (lane*4)&7. Write 8 B into the fragment-major layout.
    {
        size_t base = ((size_t)(row >> 4) * 8 + (lane >> 3)) * 512;
        int off8 = ((lane & 7) >> 1) * 128 + (row & 15) * 8 + ((lane * 4) & 7);
        *(ushort4*)(fnb2 + base + off8) = w;
    }
    float ax = bf2f(w.x), ay = bf2f(w.y), az = bf2f(w.z), aw = bf2f(w.w);
    float s2 = ax*ax + ay*ay + az*az + aw*aw;
    #pragma unroll
    for (int off = 32; off > 0; off >>= 1) s2 += __shfl_xor(s2, off, 64);
    if (lane == 0) sq[row] = s2;
    if (lane == 1) {                 // init per-row accumulators
        minpos_d2[row] = F_INF;
        maxneg_d2[row] = F_NINF;
        negsum[row] = 0.f; possum[row] = 0.f; poscnt[row] = 0.f;
    }
    if (blockIdx.x == 0 && threadIdx.x == 0) out[0] = 0.f;
}

// ---------------------------------------------------- fused MFMA passes
// WG tile: 64 i-rows x 1024 j-cols (8 j-tiles of 128). ZERO LDS, ZERO
// barriers: all A/B fragments are streamed straight from global (L1/L2)
// into registers via coalesced dwordx4 loads (fnb2 fragment-major layout),
// software-pipelined one (jt,kb) step ahead with parity-2 buffers. Loads
// return in order, so the compiler's fine-grained vmcnt(N) keeps the
// 6 prefetch loads in flight through each MFMA group and the epilogue.
// Stats accumulate in registers across the whole j-chunk; one
// reduce+atomic set per WG. grid = (8 j-chunks, 128 i-tiles).
template <int PASS>
__global__ __launch_bounds__(256, 3) void pass_kernel(
    const unsigned short* __restrict__ fnb2, const float* __restrict__ sq,
    const int* __restrict__ labels,
    float* __restrict__ minpos_d2, float* __restrict__ maxneg_d2,
    float* __restrict__ negsum, float* __restrict__ possum,
    float* __restrict__ poscnt)
{
    const int tid  = threadIdx.x;
    const int lane = tid & 63;
    const int wid  = tid >> 6;
    const int wm   = wid >> 1;       // wave row (0..1) -> 32 i-rows
    const int wn   = wid & 1;        // wave col (0..1) -> 64 j-cols
    const int q    = lane >> 4;
    const int c16  = lane & 15;
    const int i0    = blockIdx.y * 64;
    const int jbase = blockIdx.x * 1024;
    const int iblk  = (i0 >> 4) + wm * 2;          // + mt -> A row-block
    const int jblk0 = (jbase >> 4) + wn * 4;       // + jt*8 + nt -> B block

    auto ldA = [&](int kb, bf16x8* A) {
        #pragma unroll
        for (int mt = 0; mt < 2; ++mt)
            A[mt] = ((const bf16x8*)(fnb2 +
                        ((size_t)((iblk + mt) * 8 + kb)) * 512))[lane];
    };
    auto ldB = [&](int jt, int kb, bf16x8* B) {
        #pragma unroll
        for (int nt = 0; nt < 4; ++nt)
            B[nt] = ((const bf16x8*)(fnb2 +
                        ((size_t)((jblk0 + jt * 8 + nt) * 8 + kb)) * 512))[lane];
    };

    // ---- per-lane i-row invariants (8 rows: (k>>2)*16 + q*4 + (k&3)) ----
    int   labi[8]; float sqi[8];
    float mnd2[8], mxd2[8];          // pass 1 accumulators
    float tneg[8], tpos[8];          // pass 2 thresholds (d2 space)
    float ns[8], ps[8], pc[8];       // pass 2 accumulators
    #pragma unroll
    for (int k = 0; k < 8; ++k) {
        int i = i0 + wm * 32 + (k >> 2) * 16 + q * 4 + (k & 3);
        labi[k] = labels[i];
        sqi[k]  = sq[i];
        if (PASS == 1) {
            mnd2[k] = F_INF; mxd2[k] = F_NINF;
        } else {
            float mp = sqrtf(fmaxf(minpos_d2[i], 1e-12f));
            float tn = mp - 0.1f;
            tneg[k] = (tn <= 0.f) ? -3.0f : tn * tn;        // d2 > tneg
            float mx = sqrtf(fmaxf(maxneg_d2[i], 1e-12f));
            float tp = mx + 0.1f;
            tpos[k] = fminf(tp * tp, POS2);                 // d2 < tpos
            ns[k] = 0.f; ps[k] = 0.f; pc[k] = 0.f;
        }
    }

    bf16x8 Ab[2][2], Bb[2][4];       // parity-2 software pipeline
    ldA(0, Ab[0]);
    ldB(0, 0, Bb[0]);

    for (int jt = 0; jt < 8; ++jt) {
        const int j0 = jbase + jt * 128;
        int labj[4]; float sqj[4];
        #pragma unroll
        for (int nt = 0; nt < 4; ++nt) {
            int j = j0 + wn * 64 + nt * 16 + c16;
            labj[nt] = labels[j];
            sqj[nt]  = sq[j];
        }

        f32x4 acc[2][4];

        #pragma unroll
        for (int kb = 0; kb < 8; ++kb) {
            const int p = kb & 1, np = p ^ 1;
            // prefetch next (jt,kb) into the other parity
            if (kb < 7) {
                ldA(kb + 1, Ab[np]);
                ldB(jt, kb + 1, Bb[np]);
            } else if (jt < 7) {
                ldA(0, Ab[np]);
                ldB(jt + 1, 0, Bb[np]);
            }
            #pragma unroll
            for (int mt = 0; mt < 2; ++mt)
                #pragma unroll
                for (int nt = 0; nt < 4; ++nt) {
                    if (kb == 0)
                        acc[mt][nt] = __builtin_amdgcn_mfma_f32_16x16x32_bf16(
                            Ab[p][mt], Bb[p][nt],
                            (f32x4){0.f, 0.f, 0.f, 0.f}, 0, 0, 0);
                    else
                        acc[mt][nt] = __builtin_amdgcn_mfma_f32_16x16x32_bf16(
                            Ab[p][mt], Bb[p][nt], acc[mt][nt], 0, 0, 0);
                }
        }

        // ---- per-tile epilogue: accumulate into register stats ----
        // (next jt's first loads are already in flight — no barrier.)
        #pragma unroll
        for (int mt = 0; mt < 2; ++mt) {
            #pragma unroll
            for (int reg = 0; reg < 4; ++reg) {
                int k = mt * 4 + reg;
                #pragma unroll
                for (int nt = 0; nt < 4; ++nt) {
                    float dot = acc[mt][nt][reg];
                    float d2  = fmaf(-2.0f, dot, sqi[k] + sqj[nt]);
                    bool same = (labi[k] == labj[nt]);
                    if (PASS == 1) {
                        bool p2 = same && (d2 < POS2);
                        mnd2[k] = fminf(mnd2[k], p2 ? d2 : F_INF);
                        mxd2[k] = fmaxf(mxd2[k], same ? F_NINF : d2);
                    } else {
                        float dist = sqrtf(fmaxf(d2, 1e-12f));
                        bool tkp = same && (d2 < tpos[k]);
                        bool tkn = !same && (d2 > tneg[k]);
                        float arg = fmaf(same ? 2.0f : -40.0f, dist,
                                         same ? -1.4f : 40.0f);
                        float e = __expf(arg);
                        ps[k] += tkp ? e : 0.f;
                        ns[k] += tkn ? e : 0.f;
                        pc[k] += tkp ? 1.f : 0.f;
                    }
                }
            }
        }
    }

    // ---- once per WG: reduce across the 16 c16 lanes, then atomics ----
    #pragma unroll
    for (int k = 0; k < 8; ++k) {
        int i = i0 + wm * 32 + (k >> 2) * 16 + q * 4 + (k & 3);
        if (PASS == 1) {
            #pragma unroll
            for (int off = 8; off > 0; off >>= 1) {
                mnd2[k] = fminf(mnd2[k], __shfl_xor(mnd2[k], off, 64));
                mxd2[k] = fmaxf(mxd2[k], __shfl_xor(mxd2[k], off, 64));
            }
            if (c16 == 0) {
                // at most one sub-zero candidate per row (the diagonal),
                // so int ordering == float ordering for the winner
                atomicMin((int*)&minpos_d2[i], __float_as_int(mnd2[k]));
                atomicMax((int*)&maxneg_d2[i], __float_as_int(mxd2[k]));
            }
        } else {
            #pragma unroll
            for (int off = 8; off > 0; off >>= 1) {
                ns[k] += __shfl_xor(ns[k], off, 64);
                ps[k] += __shfl_xor(ps[k], off, 64);
                pc[k] += __shfl_xor(pc[k], off, 64);
            }
            if (c16 == 0) {
                atomicAdd(&negsum[i], ns[k]);
                atomicAdd(&possum[i], ps[k]);
                atomicAdd(&poscnt[i], pc[k]);
            }
        }
    }
}

// ------------------------------------------------------------- finalize
__global__ void finalize_kernel(const float* __restrict__ negsum,
                                const float* __restrict__ possum,
                                const float* __restrict__ poscnt,
                                float* out) {
    int i = blockIdx.x * 256 + threadIdx.x;
    float v = 0.f;
    if (i < NB) {
        // each neg term >= e^-40 > 0, so negsum>0 <=> neg count >= 1
        bool valid = (negsum[i] > 0.f) && (poscnt[i] >= 0.5f);
        if (valid) {
            float nl = log1pf(negsum[i]) * (1.0f / 40.0f);
            float pl = log1pf(possum[i]) / (poscnt[i] + 1e-5f);
            v = nl + pl;
        }
    }
    #pragma unroll
    for (int off = 32; off > 0; off >>= 1) v += __shfl_xor(v, off, 64);
    __shared__ float red[4];
    if ((threadIdx.x & 63) == 0) red[threadIdx.x >> 6] = v;
    __syncthreads();
    if (threadIdx.x == 0)
        atomicAdd(out, (red[0] + red[1] + red[2] + red[3]) * (1.0f / NB));
}

// ------------------------------------------------------------ launcher
extern "C" void kernel_launch(void* const* d_in, const int* in_sizes, int n_in,
                              void* d_out, int out_size, void* d_ws, size_t ws_size,
                              hipStream_t stream) {
    const float* feats  = (const float*)d_in[0];
    const int*   labels = (const int*)d_in[1];
    float* out = (float*)d_out;

    // workspace: fnb2 bf16[NB*ND] fragment-major (4 MB) then fp32 arrays
    unsigned short* fnb2 = (unsigned short*)d_ws;
    float* sqv       = (float*)(fnb2 + (size_t)NB * ND);
    float* minpos_d2 = sqv + NB;
    float* maxneg_d2 = minpos_d2 + NB;
    float* negsum    = maxneg_d2 + NB;
    float* possum    = negsum + NB;
    float* poscnt    = possum + NB;

    normalize_kernel<<<NB / 4, 256, 0, stream>>>(feats, fnb2, sqv, minpos_d2,
                                                 maxneg_d2, negsum, possum,
                                                 poscnt, out);

    dim3 grid(NB / 1024, NB / 64);   // (8 j-chunks, 128 i-tiles)
    pass_kernel<1><<<grid, 256, 0, stream>>>(fnb2, sqv, labels, minpos_d2,
                                             maxneg_d2, negsum, possum, poscnt);
    pass_kernel<2><<<grid, 256, 0, stream>>>(fnb2, sqv, labels, minpos_d2,
                                             maxneg_d2, negsum, possum, poscnt);
    finalize_kernel<<<NB / 256, 256, 0, stream>>>(negsum, possum, poscnt, out);
}

// Round 9
// 178.894 us; speedup vs baseline: 2.1129x; 2.1129x over previous
//
#include <hip/hip_runtime.h>
#include <hip/hip_fp16.h>
#include <math.h>

// Problem constants (B=8192 rows, D=256 features)
#define NB 8192
#define ND 256

using bf16x8 = __attribute__((ext_vector_type(8))) short;  // 8 bf16 in 4 VGPRs
using f32x4  = __attribute__((ext_vector_type(4))) float;  // MFMA C/D frag
using hf8    = __attribute__((ext_vector_type(8))) _Float16;

#define POS2 0.99998000f   // (1 - 1e-5)^2, pos_mask_ threshold in d2 space
#define F_INF  __int_as_float(0x7f800000)
#define F_NINF __int_as_float(0xff800000)

__device__ __forceinline__ unsigned short f2bf(float x) {  // RNE fp32->bf16
    unsigned u = __float_as_uint(x);
    return (unsigned short)((u + 0x7fffu + ((u >> 16) & 1u)) >> 16);
}
__device__ __forceinline__ float bf2f(unsigned short b) {
    return __uint_as_float(((unsigned)b) << 16);
}

// async global->LDS, 16 B per lane; LDS dest = wave-uniform base + lane*16
__device__ __forceinline__ void gload_lds16(const unsigned short* g,
                                            unsigned short* l) {
    __builtin_amdgcn_global_load_lds(
        (const __attribute__((address_space(1))) void*)g,
        (__attribute__((address_space(3))) void*)l, 16, 0, 0);
}

// ------------------------------------------- normalize (+ init folded in)
__global__ void normalize_kernel(const float* __restrict__ feats,
                                 unsigned short* __restrict__ fnb,
                                 float* __restrict__ sq,
                                 float* minpos_d2, float* maxneg_d2,
                                 float* negsum, float* possum, float* poscnt,
                                 float* out) {
    int row = blockIdx.x * 4 + (threadIdx.x >> 6);
    int lane = threadIdx.x & 63;
    float4 v = ((const float4*)(feats + (size_t)row * ND))[lane];
    float s = v.x*v.x + v.y*v.y + v.z*v.z + v.w*v.w;
    #pragma unroll
    for (int off = 32; off > 0; off >>= 1) s += __shfl_xor(s, off, 64);
    float inv = 1.0f / (sqrtf(s) + 1e-12f);
    ushort4 w;
    w.x = f2bf(v.x * inv); w.y = f2bf(v.y * inv);
    w.z = f2bf(v.z * inv); w.w = f2bf(v.w * inv);
    ((ushort4*)(fnb + (size_t)row * ND))[lane] = w;
    float ax = bf2f(w.x), ay = bf2f(w.y), az = bf2f(w.z), aw = bf2f(w.w);
    float s2 = ax*ax + ay*ay + az*az + aw*aw;
    #pragma unroll
    for (int off = 32; off > 0; off >>= 1) s2 += __shfl_xor(s2, off, 64);
    if (lane == 0) sq[row] = s2;
    if (lane == 1) {                 // init per-row accumulators
        minpos_d2[row] = F_INF;
        maxneg_d2[row] = F_NINF;
        negsum[row] = 0.f; possum[row] = 0.f; poscnt[row] = 0.f;
    }
    if (blockIdx.x == 0 && threadIdx.x == 0) out[0] = 0.f;
}

// ---------------------------------------------------- fused MFMA passes
// R6 structure (proven ~105 us): WG tile 64 i-rows x 1024 j-cols, A frags
// in registers, B staged in BK=128 chunks into a 2-buffer LDS ping-pong
// via global_load_lds. PASS 1 mines per-row min/max d2 (and, if STORE,
// writes the tile's d2 to the fp16 matrix d2h). PASS 2 is the fallback
// exp-sum pass (used only when ws_size can't hold d2h).
template <int PASS, bool STORE>
__global__ __launch_bounds__(256, 2) void pass_kernel(
    const unsigned short* __restrict__ fnb, const float* __restrict__ sq,
    const int* __restrict__ labels,
    float* __restrict__ minpos_d2, float* __restrict__ maxneg_d2,
    float* __restrict__ negsum, float* __restrict__ possum,
    float* __restrict__ poscnt, __half* __restrict__ d2h)
{
    __shared__ __align__(16) unsigned short Bs[2][128 * 128];  // 2 x 32 KB

    const int tid  = threadIdx.x;
    const int lane = tid & 63;
    const int wid  = tid >> 6;
    const int wm   = wid >> 1;       // wave row (0..1) -> 32 i-rows
    const int wn   = wid & 1;        // wave col (0..1) -> 64 j-cols
    const int q    = lane >> 4;
    const int c16  = lane & 15;
    const int i0    = blockIdx.y * 64;
    const int jbase = blockIdx.x * 1024;

    // ---- A fragments -> registers (A layout: [m=lane&15][k=q*8+j]) ----
    bf16x8 af[2][8];
    #pragma unroll
    for (int mt = 0; mt < 2; ++mt) {
        const unsigned short* arow =
            fnb + (size_t)(i0 + wm * 32 + mt * 16 + c16) * ND;
        #pragma unroll
        for (int kb = 0; kb < 8; ++kb)
            af[mt][kb] = *(const bf16x8*)(arow + kb * 32 + q * 8);
    }

    // stage chunk ck: rows of j-tile ck>>1, k-half ck&1, into Bs[ck&1].
    auto stageB = [&](int ck) {
        const int jt = ck >> 1, half = ck & 1;
        const unsigned short* src =
            fnb + (size_t)(jbase + jt * 128) * ND + half * 128;
        unsigned short* dst = &Bs[half][0];
        #pragma unroll
        for (int t = 0; t < 8; ++t) {
            int rb = wid * 32 + t * 4;
            int r  = rb + (lane >> 4);
            int sc = lane & 15;
            int c  = (sc & 8) | ((sc ^ r) & 7);
            gload_lds16(src + (size_t)r * ND + c * 8, dst + rb * 128);
        }
    };

    // ---- per-lane i-row invariants (8 rows: (k>>2)*16 + q*4 + (k&3)) ----
    int   labi[8]; float sqi[8];
    float mnd2[8], mxd2[8];          // pass 1 accumulators
    float tneg[8], tpos[8];          // pass 2 thresholds (d2 space)
    float ns[8], ps[8], pc[8];       // pass 2 accumulators
    #pragma unroll
    for (int k = 0; k < 8; ++k) {
        int i = i0 + wm * 32 + (k >> 2) * 16 + q * 4 + (k & 3);
        labi[k] = labels[i];
        sqi[k]  = sq[i];
        if (PASS == 1) {
            mnd2[k] = F_INF; mxd2[k] = F_NINF;
        } else {
            float mp = sqrtf(fmaxf(minpos_d2[i], 1e-12f));
            float tn = mp - 0.1f;
            tneg[k] = (tn <= 0.f) ? -3.0f : tn * tn;        // d2 > tneg
            float mx = sqrtf(fmaxf(maxneg_d2[i], 1e-12f));
            float tp = mx + 0.1f;
            tpos[k] = fminf(tp * tp, POS2);                 // d2 < tpos
            ns[k] = 0.f; ps[k] = 0.f; pc[k] = 0.f;
        }
    }

    stageB(0);   // cold prefetch (only un-shadowed drain)

    for (int jt = 0; jt < 8; ++jt) {
        const int j0 = jbase + jt * 128;

        f32x4 acc[2][4];
        #pragma unroll
        for (int mt = 0; mt < 2; ++mt)
            #pragma unroll
            for (int nt = 0; nt < 4; ++nt)
                acc[mt][nt] = (f32x4){0.f, 0.f, 0.f, 0.f};

        int labj[4]; float sqj[4];

        #pragma unroll
        for (int half = 0; half < 2; ++half) {
            __syncthreads();   // drains chunk jt*2+half (issued a phase ago)
            int nck = jt * 2 + half + 1;
            if (nck < 16) stageB(nck);   // prefetch into the other buffer
            if (half == 0) {
                #pragma unroll
                for (int nt = 0; nt < 4; ++nt) {
                    int j = j0 + wn * 64 + nt * 16 + c16;
                    labj[nt] = labels[j];
                    sqj[nt]  = sq[j];
                }
            }
            #pragma unroll
            for (int ks = 0; ks < 4; ++ks) {
                bf16x8 bfr[4];
                #pragma unroll
                for (int nt = 0; nt < 4; ++nt) {
                    int r  = wn * 64 + nt * 16 + c16;
                    int c  = ks * 4 + q;
                    int sc = (c & 8) | ((c ^ r) & 7);
                    bfr[nt] = *(const bf16x8*)(&Bs[half][0] + r * 128 + sc * 8);
                }
                #pragma unroll
                for (int mt = 0; mt < 2; ++mt)
                    #pragma unroll
                    for (int nt = 0; nt < 4; ++nt)
                        acc[mt][nt] = __builtin_amdgcn_mfma_f32_16x16x32_bf16(
                            af[mt][half * 4 + ks], bfr[nt], acc[mt][nt], 0, 0, 0);
            }
        }

        // ---- per-tile epilogue ----
        #pragma unroll
        for (int mt = 0; mt < 2; ++mt) {
            #pragma unroll
            for (int reg = 0; reg < 4; ++reg) {
                int k = mt * 4 + reg;
                int i = i0 + wm * 32 + mt * 16 + q * 4 + reg;
                __half* drow = STORE ?
                    (d2h + (size_t)i * NB + j0 + wn * 64 + c16) : nullptr;
                #pragma unroll
                for (int nt = 0; nt < 4; ++nt) {
                    float dot = acc[mt][nt][reg];
                    float d2  = fmaf(-2.0f, dot, sqi[k] + sqj[nt]);
                    bool same = (labi[k] == labj[nt]);
                    if (PASS == 1) {
                        bool p2 = same && (d2 < POS2);
                        mnd2[k] = fminf(mnd2[k], p2 ? d2 : F_INF);
                        mxd2[k] = fmaxf(mxd2[k], same ? F_NINF : d2);
                        if (STORE) drow[nt * 16] = __float2half(d2);
                    } else {
                        float dist = sqrtf(fmaxf(d2, 1e-12f));
                        bool tkp = same && (d2 < tpos[k]);
                        bool tkn = !same && (d2 > tneg[k]);
                        float arg = fmaf(same ? 2.0f : -40.0f, dist,
                                         same ? -1.4f : 40.0f);
                        float e = __expf(arg);
                        ps[k] += tkp ? e : 0.f;
                        ns[k] += tkn ? e : 0.f;
                        pc[k] += tkp ? 1.f : 0.f;
                    }
                }
            }
        }
    }

    // ---- once per WG: reduce across the 16 c16 lanes, then atomics ----
    #pragma unroll
    for (int k = 0; k < 8; ++k) {
        int i = i0 + wm * 32 + (k >> 2) * 16 + q * 4 + (k & 3);
        if (PASS == 1) {
            #pragma unroll
            for (int off = 8; off > 0; off >>= 1) {
                mnd2[k] = fminf(mnd2[k], __shfl_xor(mnd2[k], off, 64));
                mxd2[k] = fmaxf(mxd2[k], __shfl_xor(mxd2[k], off, 64));
            }
            if (c16 == 0) {
                // at most one sub-zero candidate per row (the diagonal),
                // so int ordering == float ordering for the winner
                atomicMin((int*)&minpos_d2[i], __float_as_int(mnd2[k]));
                atomicMax((int*)&maxneg_d2[i], __float_as_int(mxd2[k]));
            }
        } else {
            #pragma unroll
            for (int off = 8; off > 0; off >>= 1) {
                ns[k] += __shfl_xor(ns[k], off, 64);
                ps[k] += __shfl_xor(ps[k], off, 64);
                pc[k] += __shfl_xor(pc[k], off, 64);
            }
            if (c16 == 0) {
                atomicAdd(&negsum[i], ns[k]);
                atomicAdd(&possum[i], ps[k]);
                atomicAdd(&poscnt[i], pc[k]);
            }
        }
    }
}

// ------------------------------------------------- pass 2 as a d2 stream
// One WG per row: read 8192 fp16 d2 values (coalesced 16-B loads), apply
// thresholds, exp-sum. Row exclusively owned -> plain stores, no atomics.
__global__ __launch_bounds__(256) void stream_kernel(
    const __half* __restrict__ d2h, const int* __restrict__ labels,
    const float* __restrict__ minpos_d2, const float* __restrict__ maxneg_d2,
    float* __restrict__ negsum, float* __restrict__ possum,
    float* __restrict__ poscnt)
{
    const int row  = blockIdx.x;
    const int tid  = threadIdx.x;
    const int lane = tid & 63;
    const int wid  = tid >> 6;
    const int labi = labels[row];

    float mp = sqrtf(fmaxf(minpos_d2[row], 1e-12f));
    float tn = mp - 0.1f;
    float tneg = (tn <= 0.f) ? -3.0f : tn * tn;      // d2 > tneg
    float mx = sqrtf(fmaxf(maxneg_d2[row], 1e-12f));
    float tp = mx + 0.1f;
    float tpos = fminf(tp * tp, POS2);               // d2 < tpos

    float ns = 0.f, ps = 0.f, pc = 0.f;
    const _Float16* rowp = (const _Float16*)(d2h + (size_t)row * NB);

    #pragma unroll
    for (int it = 0; it < 4; ++it) {
        int j0 = it * 2048 + tid * 8;
        hf8  hv = *(const hf8*)(rowp + j0);
        int4 la = *(const int4*)(labels + j0);
        int4 lb = *(const int4*)(labels + j0 + 4);
        int labj[8] = {la.x, la.y, la.z, la.w, lb.x, lb.y, lb.z, lb.w};
        #pragma unroll
        for (int e = 0; e < 8; ++e) {
            float d2   = (float)hv[e];
            bool same  = (labj[e] == labi);
            float dist = sqrtf(fmaxf(d2, 1e-12f));
            bool tkp = same && (d2 < tpos);
            bool tkn = !same && (d2 > tneg);
            float arg = fmaf(same ? 2.0f : -40.0f, dist,
                             same ? -1.4f : 40.0f);
            float ev = __expf(arg);
            ps += tkp ? ev : 0.f;
            ns += tkn ? ev : 0.f;
            pc += tkp ? 1.f : 0.f;
        }
    }

    #pragma unroll
    for (int off = 32; off > 0; off >>= 1) {
        ns += __shfl_xor(ns, off, 64);
        ps += __shfl_xor(ps, off, 64);
        pc += __shfl_xor(pc, off, 64);
    }
    __shared__ float red[3][4];
    if (lane == 0) { red[0][wid] = ns; red[1][wid] = ps; red[2][wid] = pc; }
    __syncthreads();
    if (tid == 0) {
        negsum[row] = red[0][0] + red[0][1] + red[0][2] + red[0][3];
        possum[row] = red[1][0] + red[1][1] + red[1][2] + red[1][3];
        poscnt[row] = red[2][0] + red[2][1] + red[2][2] + red[2][3];
    }
}

// ------------------------------------------------------------- finalize
__global__ void finalize_kernel(const float* __restrict__ negsum,
                                const float* __restrict__ possum,
                                const float* __restrict__ poscnt,
                                float* out) {
    int i = blockIdx.x * 256 + threadIdx.x;
    float v = 0.f;
    if (i < NB) {
        // each neg term >= e^-40 > 0, so negsum>0 <=> neg count >= 1
        bool valid = (negsum[i] > 0.f) && (poscnt[i] >= 0.5f);
        if (valid) {
            float nl = log1pf(negsum[i]) * (1.0f / 40.0f);
            float pl = log1pf(possum[i]) / (poscnt[i] + 1e-5f);
            v = nl + pl;
        }
    }
    #pragma unroll
    for (int off = 32; off > 0; off >>= 1) v += __shfl_xor(v, off, 64);
    __shared__ float red[4];
    if ((threadIdx.x & 63) == 0) red[threadIdx.x >> 6] = v;
    __syncthreads();
    if (threadIdx.x == 0)
        atomicAdd(out, (red[0] + red[1] + red[2] + red[3]) * (1.0f / NB));
}

// ------------------------------------------------------------ launcher
extern "C" void kernel_launch(void* const* d_in, const int* in_sizes, int n_in,
                              void* d_out, int out_size, void* d_ws, size_t ws_size,
                              hipStream_t stream) {
    const float* feats  = (const float*)d_in[0];
    const int*   labels = (const int*)d_in[1];
    float* out = (float*)d_out;

    // workspace: fnb bf16[NB*ND] (4 MB) | 6 fp32 row arrays (192 KB) |
    //            d2h fp16[NB*NB] (128 MB, if it fits)
    unsigned short* fnb = (unsigned short*)d_ws;
    float* sqv       = (float*)(fnb + (size_t)NB * ND);
    float* minpos_d2 = sqv + NB;
    float* maxneg_d2 = minpos_d2 + NB;
    float* negsum    = maxneg_d2 + NB;
    float* possum    = negsum + NB;
    float* poscnt    = possum + NB;
    __half* d2h      = (__half*)(poscnt + NB);

    const size_t need = (size_t)NB * ND * 2 + 6u * NB * 4 + (size_t)NB * NB * 2;
    const bool use_stream = (ws_size >= need);   // constant per problem

    normalize_kernel<<<NB / 4, 256, 0, stream>>>(feats, fnb, sqv, minpos_d2,
                                                 maxneg_d2, negsum, possum,
                                                 poscnt, out);

    dim3 grid(NB / 1024, NB / 64);   // (8 j-chunks, 128 i-tiles)
    if (use_stream) {
        pass_kernel<1, true><<<grid, 256, 0, stream>>>(
            fnb, sqv, labels, minpos_d2, maxneg_d2, negsum, possum, poscnt, d2h);
        stream_kernel<<<NB, 256, 0, stream>>>(d2h, labels, minpos_d2,
                                              maxneg_d2, negsum, possum, poscnt);
    } else {
        pass_kernel<1, false><<<grid, 256, 0, stream>>>(
            fnb, sqv, labels, minpos_d2, maxneg_d2, negsum, possum, poscnt, d2h);
        pass_kernel<2, false><<<grid, 256, 0, stream>>>(
            fnb, sqv, labels, minpos_d2, maxneg_d2, negsum, possum, poscnt, d2h);
    }
    finalize_kernel<<<NB / 256, 256, 0, stream>>>(negsum, possum, poscnt, out);
}